// Round 2
// baseline (259.810 us; speedup 1.0000x reference)
//
#include <hip/hip_runtime.h>

#define B_   128
#define L_   196
#define ENC_ 2048
#define DEC_ 512
#define ATT_ 512
#define M_   (B_ * L_)   // 25088

typedef _Float16 f16x4 __attribute__((ext_vector_type(4)));
typedef _Float16 f16x8 __attribute__((ext_vector_type(8)));
typedef __fp16   h16x2 __attribute__((ext_vector_type(2)));
typedef float    f32x4 __attribute__((ext_vector_type(4)));

// ---------------- ws layout ----------------
// [0,          262144)   dec_map  f32 [128][512]
// [262144,    2359296)   WeT      f16 [512][2048]   (N-major, K contiguous)
// [2359296,   2760704)   partial  f32 [4][25088]    (per-N-tile partial scores)

// We [2048][512] fp32 -> WeT [512][2048] f16 (transposed)
__global__ void wet_kernel(const float* __restrict__ We, _Float16* __restrict__ WeT) {
    int idx = blockIdx.x * 256 + threadIdx.x;      // over 512*2048 = 1M
    int n = idx >> 11;
    int k = idx & 2047;
    WeT[idx] = (_Float16)We[k * ATT_ + n];
}

// dec_map[b][a] = decoder_hidden[b] . Wd[:,a] + bd[a]
__global__ void decmap_kernel(const float* __restrict__ dh, const float* __restrict__ Wd,
                              const float* __restrict__ bd, float* __restrict__ dec) {
    int b = blockIdx.x;       // 128
    int a = threadIdx.x;      // 512
    float acc = bd[a];
    const float* dhp = dh + b * DEC_;
#pragma unroll 8
    for (int k = 0; k < DEC_; ++k) acc += dhp[k] * Wd[k * ATT_ + a];
    dec[b * ATT_ + a] = acc;
}

// Main fused GEMM: per block, C-tile 128(M) x 128(N), K=2048 loop, f16 MFMA,
// epilogue: partial_score[ntile][row] += sum_n tanh(acc + be[n] + dec[b][n]) * wa[n]
__global__ __launch_bounds__(256, 2)
void gemm_score_kernel(const float* __restrict__ enc,
                       const _Float16* __restrict__ WeT,
                       const float* __restrict__ be,
                       const float* __restrict__ wa,
                       const float* __restrict__ dec,
                       float* __restrict__ partial) {
    __shared__ __align__(16) _Float16 As[128][72];   // pad 64->72: stride 144B = 9*16B
    __shared__ __align__(16) _Float16 Bs[128][72];
    __shared__ float red[2][128];

    // XCD-chunked swizzle: keep the 4 ntile-siblings of one mtile on one XCD.
    // 784 blocks; xcd = bid%8 (HW round-robin), sid chunked per xcd.
    int bid = blockIdx.x;
    int sid = (bid & 7) * 98 + (bid >> 3);           // bijective on [0,784)
    int mtile = sid >> 2;                            // 0..195
    int ntile = sid & 3;                             // 0..3

    int tid  = threadIdx.x;
    int lane = tid & 63, wid = tid >> 6;
    int wm = wid >> 1, wn = wid & 1;                 // 2x2 waves of 64x64
    int l15 = lane & 15, lg = lane >> 4;

    int srow = tid & 127;                            // staging row (distinct per lane)
    int ksel = tid >> 7;                             // 0/1 -> K half

    const float*    ag = enc + (size_t)(mtile * 128 + srow) * ENC_ + ksel * 32;
    const _Float16* bg = WeT + (size_t)(ntile * 128 + srow) * ENC_ + ksel * 32;

    f32x4 acc[4][4];
#pragma unroll
    for (int mi = 0; mi < 4; ++mi)
#pragma unroll
        for (int ni = 0; ni < 4; ++ni) acc[mi][ni] = (f32x4){0.f, 0.f, 0.f, 0.f};

    for (int kt = 0; kt < ENC_ / 64; ++kt) {
        __syncthreads();
        // stage A: 128x64 fp32 -> f16, 8 x float4 per thread
#pragma unroll
        for (int i = 0; i < 8; ++i) {
            float4 v = *reinterpret_cast<const float4*>(ag + kt * 64 + i * 4);
            union { h16x2 h2[2]; f16x4 h4; } u;
            u.h2[0] = __builtin_amdgcn_cvt_pkrtz(v.x, v.y);
            u.h2[1] = __builtin_amdgcn_cvt_pkrtz(v.z, v.w);
            *reinterpret_cast<f16x4*>(&As[srow][ksel * 32 + i * 4]) = u.h4;
        }
        // stage B: 128x64 f16 direct copy, 4 x 16B per thread
#pragma unroll
        for (int i = 0; i < 4; ++i) {
            *reinterpret_cast<f16x8*>(&Bs[srow][ksel * 32 + i * 8]) =
                *reinterpret_cast<const f16x8*>(bg + kt * 64 + i * 8);
        }
        __syncthreads();
#pragma unroll
        for (int ks = 0; ks < 2; ++ks) {
            int kb = ks * 32 + lg * 8;
            f16x8 af[4], bf[4];
#pragma unroll
            for (int mi = 0; mi < 4; ++mi)
                af[mi] = *reinterpret_cast<const f16x8*>(&As[wm * 64 + mi * 16 + l15][kb]);
#pragma unroll
            for (int ni = 0; ni < 4; ++ni)
                bf[ni] = *reinterpret_cast<const f16x8*>(&Bs[wn * 64 + ni * 16 + l15][kb]);
#pragma unroll
            for (int mi = 0; mi < 4; ++mi)
#pragma unroll
                for (int ni = 0; ni < 4; ++ni)
                    acc[mi][ni] = __builtin_amdgcn_mfma_f32_16x16x32_f16(
                        af[mi], bf[ni], acc[mi][ni], 0, 0, 0);
        }
    }

    // Epilogue: x = acc + be[n] + dec[b][n]; t = tanh(x); rowsum += t*wa[n]
    float rsum[4][4];
#pragma unroll
    for (int mi = 0; mi < 4; ++mi)
#pragma unroll
        for (int j = 0; j < 4; ++j) rsum[mi][j] = 0.f;

    int nb = ntile * 128 + wn * 64;
    int rb = mtile * 128 + wm * 64;
#pragma unroll
    for (int ni = 0; ni < 4; ++ni) {
        int n = nb + ni * 16 + l15;
        float wav = wa[n];
        float bev = be[n];
#pragma unroll
        for (int mi = 0; mi < 4; ++mi) {
#pragma unroll
            for (int j = 0; j < 4; ++j) {
                int row = rb + mi * 16 + lg * 4 + j;    // C/D: col=lane&15, row=(lane>>4)*4+reg
                int b = row / L_;
                float x = acc[mi][ni][j] + bev + dec[b * ATT_ + n];
                float e = __expf(2.0f * x);
                float t = 1.0f - 2.0f / (e + 1.0f);     // tanh(x), inf-safe
                rsum[mi][j] += t * wav;
            }
        }
    }
    // reduce over the 16 lanes holding the same rows (l15 = n-direction)
#pragma unroll
    for (int mi = 0; mi < 4; ++mi) {
#pragma unroll
        for (int j = 0; j < 4; ++j) {
            float v = rsum[mi][j];
            v += __shfl_xor(v, 1);
            v += __shfl_xor(v, 2);
            v += __shfl_xor(v, 4);
            v += __shfl_xor(v, 8);
            if (l15 == 0) red[wn][wm * 64 + mi * 16 + lg * 4 + j] = v;
        }
    }
    __syncthreads();
    if (tid < 128)
        partial[(size_t)ntile * M_ + mtile * 128 + tid] = red[0][tid] + red[1][tid];
}

// softmax over L per batch row. ba cancels in softmax -> skipped.
__global__ void softmax_kernel(const float* __restrict__ partial, float* __restrict__ alphas) {
    int b = blockIdx.x, t = threadIdx.x;     // 128 blocks x 256 threads
    int lane = t & 63, wid = t >> 6;
    __shared__ float red[4];
    float s = 0.f, val = -1e30f;
    if (t < L_) {
        int r = b * L_ + t;
        s = partial[r] + partial[M_ + r] + partial[2 * M_ + r] + partial[3 * M_ + r];
        val = s;
    }
    float m = val;
#pragma unroll
    for (int off = 1; off < 64; off <<= 1) m = fmaxf(m, __shfl_xor(m, off));
    if (lane == 0) red[wid] = m;
    __syncthreads();
    m = fmaxf(fmaxf(red[0], red[1]), fmaxf(red[2], red[3]));
    float e = (t < L_) ? __expf(s - m) : 0.f;
    float sum = e;
#pragma unroll
    for (int off = 1; off < 64; off <<= 1) sum += __shfl_xor(sum, off);
    __syncthreads();
    if (lane == 0) red[wid] = sum;
    __syncthreads();
    sum = red[0] + red[1] + red[2] + red[3];
    if (t < L_) alphas[b * L_ + t] = e / sum;
}

// context[b][e] = sum_l alphas[b][l] * enc[b][l][e]   (memory-bound pass)
__global__ void context_kernel(const float* __restrict__ enc, const float* __restrict__ alphas,
                               float* __restrict__ ctx) {
    int b = blockIdx.x >> 2;                  // 128 b x 4 e-chunks = 512 blocks
    int ec = blockIdx.x & 3;
    int e = ec * 512 + threadIdx.x * 2;
    const float* ep = enc + (size_t)b * L_ * ENC_ + e;
    const float* ap = alphas + b * L_;
    float ax = 0.f, ay = 0.f;
#pragma unroll 4
    for (int l = 0; l < L_; ++l) {
        float a = ap[l];
        float2 v = *reinterpret_cast<const float2*>(ep + (size_t)l * ENC_);
        ax += a * v.x;
        ay += a * v.y;
    }
    float2 r; r.x = ax; r.y = ay;
    *reinterpret_cast<float2*>(&ctx[b * ENC_ + e]) = r;
}

extern "C" void kernel_launch(void* const* d_in, const int* in_sizes, int n_in,
                              void* d_out, int out_size, void* d_ws, size_t ws_size,
                              hipStream_t stream) {
    const float* enc = (const float*)d_in[0];
    const float* dh  = (const float*)d_in[1];
    const float* We  = (const float*)d_in[2];
    const float* be  = (const float*)d_in[3];
    const float* Wd  = (const float*)d_in[4];
    const float* bd  = (const float*)d_in[5];
    const float* wa  = (const float*)d_in[6];
    // d_in[7] = ba: shifts all scores equally -> cancels in softmax, unused.

    float* out    = (float*)d_out;
    float* ctx    = out;               // [128][2048]
    float* alphas = out + B_ * ENC_;   // [128][196]

    char* ws = (char*)d_ws;
    float*    dec     = (float*)ws;                            // 256 KiB
    _Float16* WeT     = (_Float16*)(ws + 262144);              // 2 MiB
    float*    partial = (float*)(ws + 262144 + 2097152);       // 392 KiB

    hipLaunchKernelGGL(wet_kernel,        dim3(4096), dim3(256), 0, stream, We, WeT);
    hipLaunchKernelGGL(decmap_kernel,     dim3(128),  dim3(512), 0, stream, dh, Wd, bd, dec);
    hipLaunchKernelGGL(gemm_score_kernel, dim3(784),  dim3(256), 0, stream, enc, WeT, be, wa, dec, partial);
    hipLaunchKernelGGL(softmax_kernel,    dim3(128),  dim3(256), 0, stream, partial, alphas);
    hipLaunchKernelGGL(context_kernel,    dim3(512),  dim3(256), 0, stream, enc, alphas, ctx);
}